// Round 1
// baseline (616.604 us; speedup 1.0000x reference)
//
#include <hip/hip_runtime.h>
#include <math.h>

#define PI2_256 0.024543692606170259674f  // 2*pi/256

// ---------------------------------------------------------------------------
// Problem dims: B=8, C=64, H=256, W=256, M1=M2=16, MLP_HID=32
// Workspace layout (floats):
//   Xr [B][C][32][16]          offset 0        (262144)
//   Xi                          offset 262144
//   Yr [B][16kx][32m][64o]      offset 524288
//   Yi                          offset 786432
//   Aw [B][H][32k][64o]         offset 1048576  (4194304)
// total 5242880 floats = 21 MB
// ---------------------------------------------------------------------------

__device__ __forceinline__ void fma4(float4& a, float s, const float4& v) {
    a.x += s * v.x; a.y += s * v.y; a.z += s * v.z; a.w += s * v.w;
}

__device__ __forceinline__ float gelu_tanh(float v) {
    // jax.nn.gelu approximate=True: 0.5*v*(1+tanh(sqrt(2/pi)*(v+0.044715 v^3)))
    float t = 0.7978845608028654f * v * (1.0f + 0.044715f * v * v);
    float at = fabsf(t);
    float e = __expf(-2.0f * at);
    float th = (1.0f - e) / (1.0f + e);
    th = copysignf(th, t);
    return 0.5f * v * (1.0f + th);
}

// ---------------------------------------------------------------------------
// Kernel A: forward DFT, keeps ky in {0..15} u {240..255}, kx in {0..15}.
// grid (64 c, 8 b), 256 threads. Chunked over 16 h-rows.
// ---------------------------------------------------------------------------
__global__ __launch_bounds__(256) void k_fwd(const float* __restrict__ x,
                                             float* __restrict__ Xr,
                                             float* __restrict__ Xi) {
    int b = blockIdx.y, c = blockIdx.x;
    const float* img = x + ((size_t)(b * 64 + c)) * 65536;
    __shared__ float xs[16 * 260];          // 16 rows, padded 260 (f4 stride 65)
    __shared__ float xwr[256], xwi[256];    // [16 h][16 kx]

    int tid = threadIdx.x;
    int kx = tid & 15;
    int hl = tid >> 4;          // row role in w-DFT phase
    int m16 = tid >> 4;         // mode role in h-accumulate phase

    // rotation step e^{-2*pi*i*kx/256} tracked as (cos, -sin)
    float steps, stepc;
    __sincosf(PI2_256 * (float)kx, &steps, &stepc);
    steps = -steps;

    float a1r = 0.f, a1i = 0.f, a2r = 0.f, a2i = 0.f;
    int f1 = m16, f2 = 240 + m16;

    for (int chunk = 0; chunk < 16; ++chunk) {
        int hbase = chunk * 16;
        // stage 16 rows (1024 float4)
        for (int q = 0; q < 4; ++q) {
            int f4 = tid + q * 256;
            int row = f4 >> 6, col = f4 & 63;
            float4 v = ((const float4*)(img + (hbase + row) * 256))[col];
            ((float4*)xs)[row * 65 + col] = v;
        }
        __syncthreads();

        // w-DFT: thread (hl, kx): Xw = sum_w x[w] * e^{-2 pi i kx w/256}
        float cr = 1.f, ci = 0.f;   // (cos, -sin) running twiddle
        float swr = 0.f, swi = 0.f;
        const float4* xrow = (const float4*)(xs + hl * 260);
        for (int w4 = 0; w4 < 64; ++w4) {
            float4 xv = xrow[w4];
            { float xe = xv.x; swr += xe * cr; swi += xe * ci;
              float nc = cr * stepc - ci * steps; ci = cr * steps + ci * stepc; cr = nc; }
            { float xe = xv.y; swr += xe * cr; swi += xe * ci;
              float nc = cr * stepc - ci * steps; ci = cr * steps + ci * stepc; cr = nc; }
            { float xe = xv.z; swr += xe * cr; swi += xe * ci;
              float nc = cr * stepc - ci * steps; ci = cr * steps + ci * stepc; cr = nc; }
            { float xe = xv.w; swr += xe * cr; swi += xe * ci;
              float nc = cr * stepc - ci * steps; ci = cr * steps + ci * stepc; cr = nc; }
        }
        xwr[hl * 16 + kx] = swr;
        xwi[hl * 16 + kx] = swi;
        __syncthreads();

        // h-accumulate: thread (m16, kx) handles modes m16 and m16+16
        for (int hh = 0; hh < 16; ++hh) {
            int h = hbase + hh;
            float wr = xwr[hh * 16 + kx], wi = xwi[hh * 16 + kx];
            float s1, c1, s2, c2;
            __sincosf(PI2_256 * (float)((f1 * h) & 255), &s1, &c1);
            __sincosf(PI2_256 * (float)((f2 * h) & 255), &s2, &c2);
            // multiply by e^{-i theta} = c - i s
            a1r += wr * c1 + wi * s1;  a1i += wi * c1 - wr * s1;
            a2r += wr * c2 + wi * s2;  a2i += wi * c2 - wr * s2;
        }
        __syncthreads();
    }
    int base = ((b * 64 + c) * 32) * 16;
    Xr[base + m16 * 16 + kx]        = a1r;
    Xi[base + m16 * 16 + kx]        = a1i;
    Xr[base + (m16 + 16) * 16 + kx] = a2r;
    Xi[base + (m16 + 16) * 16 + kx] = a2i;
}

// ---------------------------------------------------------------------------
// Kernel B: complex channel mix per mode.  grid (32 m, 8 b), 256 threads.
// Y[b][kx][m][o] = sum_i X[b][i][m][kx] * W[i][o][mm][kx]
// ---------------------------------------------------------------------------
__global__ __launch_bounds__(256) void k_mix(const float* __restrict__ Xr,
                                             const float* __restrict__ Xi,
                                             const float* __restrict__ w1r,
                                             const float* __restrict__ w1i,
                                             const float* __restrict__ w2r,
                                             const float* __restrict__ w2i,
                                             float* __restrict__ Yr,
                                             float* __restrict__ Yi) {
    int m = blockIdx.x, b = blockIdx.y;
    __shared__ float Xsr[1024], Xsi[1024];   // [64 i][16 kx]
    int tid = threadIdx.x;
    for (int q = 0; q < 4; ++q) {
        int slot = tid + q * 256;
        int i = slot >> 4, kx = slot & 15;
        Xsr[slot] = Xr[((b * 64 + i) * 32 + m) * 16 + kx];
        Xsi[slot] = Xi[((b * 64 + i) * 32 + m) * 16 + kx];
    }
    __syncthreads();

    const float* Wr; const float* Wi; int mm;
    if (m < 16) { Wr = w1r; Wi = w1i; mm = m; }
    else        { Wr = w2r; Wi = w2i; mm = m - 16; }

    int kx = tid & 15, og = tid >> 4;
    float ar[4] = {0, 0, 0, 0}, ai[4] = {0, 0, 0, 0};
    for (int i = 0; i < 64; ++i) {
        float xr = Xsr[i * 16 + kx], xi2 = Xsi[i * 16 + kx];
#pragma unroll
        for (int t = 0; t < 4; ++t) {
            int o = og + t * 16;
            int widx = ((i * 64 + o) * 16 + mm) * 16 + kx;
            float wr = Wr[widx], wi = Wi[widx];
            ar[t] += xr * wr - xi2 * wi;
            ai[t] += xr * wi + xi2 * wr;
        }
    }
#pragma unroll
    for (int t = 0; t < 4; ++t) {
        int o = og + t * 16;
        int yidx = ((b * 16 + kx) * 32 + m) * 64 + o;
        Yr[yidx] = ar[t];
        Yi[yidx] = ai[t];
    }
}

// ---------------------------------------------------------------------------
// Kernel C: expand modes along h.
// Aw[b][h][2kx][o]   =  sc * Re(U),  Aw[b][h][2kx+1][o] = -sc * Im(U)
// U[b,o,h,kx] = sum_m Y[b,o,m,kx] e^{+2 pi i f(m) h / 256},  sc = (kx?2:1)/65536
// grid 2048 = b(8)*kx(16)*hq(16), 64 threads (o).
// ---------------------------------------------------------------------------
__global__ __launch_bounds__(64) void k_expand(const float* __restrict__ Yr,
                                               const float* __restrict__ Yi,
                                               float* __restrict__ Aw) {
    int bid = blockIdx.x;
    int hq = bid & 15, kx = (bid >> 4) & 15, b = bid >> 8;
    int o = threadIdx.x;

    float yr[32], yi[32];
    int ybase = ((b * 16 + kx) * 32) * 64 + o;
#pragma unroll
    for (int mm = 0; mm < 32; ++mm) {
        yr[mm] = Yr[ybase + mm * 64];
        yi[mm] = Yi[ybase + mm * 64];
    }
    float sc = (kx == 0 ? 1.0f : 2.0f) * (1.0f / 65536.0f);

    for (int hl = 0; hl < 16; ++hl) {
        int h = hq * 16 + hl;
        float sts, stc;
        __sincosf(PI2_256 * (float)h, &sts, &stc);  // step e^{+i 2 pi h/256}
        float tc = 1.f, ts = 0.f, ur = 0.f, ui = 0.f;
#pragma unroll
        for (int mm = 0; mm < 16; ++mm) {
            ur += yr[mm] * tc - yi[mm] * ts;
            ui += yr[mm] * ts + yi[mm] * tc;
            float nc = tc * stc - ts * sts; ts = tc * sts + ts * stc; tc = nc;
        }
        { float s2, c2; __sincosf(PI2_256 * (float)((240 * h) & 255), &s2, &c2);
          tc = c2; ts = s2; }
#pragma unroll
        for (int mm = 16; mm < 32; ++mm) {
            ur += yr[mm] * tc - yi[mm] * ts;
            ui += yr[mm] * ts + yi[mm] * tc;
            float nc = tc * stc - ts * sts; ts = tc * sts + ts * stc; tc = nc;
        }
        int abase = ((b * 256 + h) * 32 + 2 * kx) * 64 + o;
        Aw[abase]      =  sc * ur;
        Aw[abase + 64] = -sc * ui;
    }
}

// ---------------------------------------------------------------------------
// Kernel D: fused  spectral-recon + skip-conv + bias + MLP(gelu) + residual.
// One block per (b,h) row.  256 threads.  ~144.5 KB LDS.
// Thread tiling: oq = tid>>5 (8 groups), wq = tid&31.
//   o tile = {oq*4..+3} u {32+oq*4..+3};  w tile = {wq*4..+3} u {128+wq*4..+3}
// -> all LDS reads are lane-stride-16B (conflict-free).
// ---------------------------------------------------------------------------
#define FMA_BLK(A, wt, oh, xv0, xv1)                                   \
    fma4(A[oh][0][0], wt.x, xv0); fma4(A[oh][0][1], wt.x, xv1);        \
    fma4(A[oh][1][0], wt.y, xv0); fma4(A[oh][1][1], wt.y, xv1);        \
    fma4(A[oh][2][0], wt.z, xv0); fma4(A[oh][2][1], wt.z, xv1);        \
    fma4(A[oh][3][0], wt.w, xv0); fma4(A[oh][3][1], wt.w, xv1);

__global__ __launch_bounds__(256) void k_fuse(const float* __restrict__ x,
                                              const float* __restrict__ Aw,
                                              const float* __restrict__ skw,
                                              const float* __restrict__ skb,
                                              const float* __restrict__ m1w,
                                              const float* __restrict__ m1b,
                                              const float* __restrict__ m2w,
                                              const float* __restrict__ m2b,
                                              float* __restrict__ out) {
    __shared__ float xs[64 * 260];   // x row-block, then x1   (f4 stride 65)
    __shared__ float Fb[32 * 260];   // cos/sin table, then h1 (f4 stride 65)
    __shared__ float As[32 * 68];    // spectral A  [k][o]
    __shared__ float sw[64 * 68];    // skip weight [i][o]
    __shared__ float w1[64 * 36];    // mlp w1      [o][j]
    __shared__ float w2[32 * 68];    // mlp w2      [j][o]
    __shared__ float bs[64], b1s[32], b2s[64];

    int bid = blockIdx.x;
    int b = bid >> 8, h = bid & 255;
    int tid = threadIdx.x;

    const float* xrow0 = x + ((size_t)(b * 64) * 256 + h) * 256;

    // ---- stage x rows: 4096 float4 ----
    for (int q = 0; q < 16; ++q) {
        int f4 = tid + q * 256;
        int row = f4 >> 6, col = f4 & 63;
        float4 v = ((const float4*)(xrow0 + (size_t)row * 65536))[col];
        ((float4*)xs)[row * 65 + col] = v;
    }
    // ---- stage A ----
    {
        const float* ab = Aw + ((size_t)(b * 256 + h) * 32) * 64;
        for (int q = 0; q < 8; ++q) {
            int slot = tid + q * 256;
            int k = slot >> 6, o = slot & 63;
            As[k * 68 + o] = ab[slot];
        }
    }
    // ---- build F table: F[2kx][w]=cos, F[2kx+1][w]=sin ----
    {
        int w = tid;
#pragma unroll
        for (int kx2 = 0; kx2 < 16; ++kx2) {
            float s, c;
            __sincosf(PI2_256 * (float)((kx2 * w) & 255), &s, &c);
            Fb[(2 * kx2) * 260 + w]     = c;
            Fb[(2 * kx2 + 1) * 260 + w] = s;
        }
    }
    // ---- stage transposed weights + biases ----
    for (int q = 0; q < 16; ++q) {
        int slot = tid + q * 256;          // skw[o][i] -> sw[i][o]
        int o = slot >> 6, i = slot & 63;
        sw[i * 68 + o] = skw[slot];
    }
    for (int q = 0; q < 8; ++q) {
        int slot = tid + q * 256;          // m1w[j][o] -> w1[o][j]
        int j = slot >> 6, o = slot & 63;
        w1[o * 36 + j] = m1w[slot];
    }
    for (int q = 0; q < 8; ++q) {
        int slot = tid + q * 256;          // m2w[o][j] -> w2[j][o]
        int o = slot >> 5, j = slot & 31;
        w2[j * 68 + o] = m2w[slot];
    }
    if (tid < 64) bs[tid]  = skb[tid];
    if (tid < 32) b1s[tid] = m1b[tid];
    if (tid < 64) b2s[tid] = m2b[tid];
    __syncthreads();

    int oq = tid >> 5, wq = tid & 31;
    int o0 = oq * 4, w0 = wq * 4;

    // ================= phase 1: x1 = skip(x) + spectral + bias ==============
    float4 a[2][4][2];
#pragma unroll
    for (int p = 0; p < 2; ++p)
#pragma unroll
        for (int i = 0; i < 4; ++i)
#pragma unroll
            for (int q = 0; q < 2; ++q) a[p][i][q] = make_float4(0, 0, 0, 0);

    for (int k = 0; k < 64; ++k) {
        float4 wt0 = *(const float4*)&sw[k * 68 + o0];
        float4 wt1 = *(const float4*)&sw[k * 68 + 32 + o0];
        float4 xv0 = *(const float4*)&xs[k * 260 + w0];
        float4 xv1 = *(const float4*)&xs[k * 260 + 128 + w0];
        FMA_BLK(a, wt0, 0, xv0, xv1);
        FMA_BLK(a, wt1, 1, xv0, xv1);
    }
    for (int k = 0; k < 32; ++k) {
        float4 wt0 = *(const float4*)&As[k * 68 + o0];
        float4 wt1 = *(const float4*)&As[k * 68 + 32 + o0];
        float4 xv0 = *(const float4*)&Fb[k * 260 + w0];
        float4 xv1 = *(const float4*)&Fb[k * 260 + 128 + w0];
        FMA_BLK(a, wt0, 0, xv0, xv1);
        FMA_BLK(a, wt1, 1, xv0, xv1);
    }
    __syncthreads();   // everyone done reading xs/Fb
    // write x1 over xs
#pragma unroll
    for (int p = 0; p < 2; ++p)
#pragma unroll
        for (int i = 0; i < 4; ++i) {
            int o = p * 32 + o0 + i;
            float bb = bs[o];
#pragma unroll
            for (int q = 0; q < 2; ++q) {
                float4 v = a[p][i][q];
                v.x += bb; v.y += bb; v.z += bb; v.w += bb;
                ((float4*)xs)[o * 65 + q * 32 + wq] = v;
            }
        }
    __syncthreads();

    // ================= phase 2: h1 = gelu(w1 . x1 + b1) =====================
    int j0 = o0;   // 8 groups * 4 = 32 hidden
    float4 a2[4][2];
#pragma unroll
    for (int i = 0; i < 4; ++i)
#pragma unroll
        for (int q = 0; q < 2; ++q) a2[i][q] = make_float4(0, 0, 0, 0);

    for (int o = 0; o < 64; ++o) {
        float4 wt  = *(const float4*)&w1[o * 36 + j0];
        float4 xv0 = ((const float4*)xs)[o * 65 + wq];
        float4 xv1 = ((const float4*)xs)[o * 65 + 32 + wq];
        fma4(a2[0][0], wt.x, xv0); fma4(a2[0][1], wt.x, xv1);
        fma4(a2[1][0], wt.y, xv0); fma4(a2[1][1], wt.y, xv1);
        fma4(a2[2][0], wt.z, xv0); fma4(a2[2][1], wt.z, xv1);
        fma4(a2[3][0], wt.w, xv0); fma4(a2[3][1], wt.w, xv1);
    }
    __syncthreads();   // phase-1 table reads of Fb are long done; x1 reads done
#pragma unroll
    for (int i = 0; i < 4; ++i) {
        float bb = b1s[j0 + i];
#pragma unroll
        for (int q = 0; q < 2; ++q) {
            float4 v = a2[i][q];
            v.x = gelu_tanh(v.x + bb);
            v.y = gelu_tanh(v.y + bb);
            v.z = gelu_tanh(v.z + bb);
            v.w = gelu_tanh(v.w + bb);
            ((float4*)Fb)[(j0 + i) * 65 + q * 32 + wq] = v;  // h1
        }
    }
    __syncthreads();

    // ================= phase 3: out = x + w2 . h1 + b2 ======================
    float4 a3[2][4][2];
#pragma unroll
    for (int p = 0; p < 2; ++p)
#pragma unroll
        for (int i = 0; i < 4; ++i)
#pragma unroll
            for (int q = 0; q < 2; ++q) a3[p][i][q] = make_float4(0, 0, 0, 0);

    // prefetch residual x (global, coalesced)
    float4 res[2][4][2];
#pragma unroll
    for (int p = 0; p < 2; ++p)
#pragma unroll
        for (int i = 0; i < 4; ++i) {
            int o = p * 32 + o0 + i;
            const float4* xg = (const float4*)(x + (((size_t)(b * 64 + o)) * 256 + h) * 256);
#pragma unroll
            for (int q = 0; q < 2; ++q) res[p][i][q] = xg[q * 32 + wq];
        }

    for (int j = 0; j < 32; ++j) {
        float4 wt0 = *(const float4*)&w2[j * 68 + o0];
        float4 wt1 = *(const float4*)&w2[j * 68 + 32 + o0];
        float4 xv0 = ((const float4*)Fb)[j * 65 + wq];
        float4 xv1 = ((const float4*)Fb)[j * 65 + 32 + wq];
        FMA_BLK(a3, wt0, 0, xv0, xv1);
        FMA_BLK(a3, wt1, 1, xv0, xv1);
    }

#pragma unroll
    for (int p = 0; p < 2; ++p)
#pragma unroll
        for (int i = 0; i < 4; ++i) {
            int o = p * 32 + o0 + i;
            float bb = b2s[o];
            float4* og = (float4*)(out + (((size_t)(b * 64 + o)) * 256 + h) * 256);
#pragma unroll
            for (int q = 0; q < 2; ++q) {
                float4 v = a3[p][i][q];
                float4 r = res[p][i][q];
                v.x += bb + r.x; v.y += bb + r.y; v.z += bb + r.z; v.w += bb + r.w;
                og[q * 32 + wq] = v;
            }
        }
}

// ---------------------------------------------------------------------------
extern "C" void kernel_launch(void* const* d_in, const int* in_sizes, int n_in,
                              void* d_out, int out_size, void* d_ws, size_t ws_size,
                              hipStream_t stream) {
    const float* x   = (const float*)d_in[0];
    const float* w1r = (const float*)d_in[1];
    const float* w1i = (const float*)d_in[2];
    const float* w2r = (const float*)d_in[3];
    const float* w2i = (const float*)d_in[4];
    const float* skw = (const float*)d_in[5];
    const float* skb = (const float*)d_in[6];
    const float* m1w = (const float*)d_in[7];
    const float* m1b = (const float*)d_in[8];
    const float* m2w = (const float*)d_in[9];
    const float* m2b = (const float*)d_in[10];
    float* out = (float*)d_out;

    float* ws = (float*)d_ws;
    float* Xr = ws;
    float* Xi = ws + 262144;
    float* Yr = ws + 524288;
    float* Yi = ws + 786432;
    float* Aw = ws + 1048576;   // 16.8 MB; total ws use = 21 MB

    hipLaunchKernelGGL(k_fwd,    dim3(64, 8), dim3(256), 0, stream, x, Xr, Xi);
    hipLaunchKernelGGL(k_mix,    dim3(32, 8), dim3(256), 0, stream,
                       Xr, Xi, w1r, w1i, w2r, w2i, Yr, Yi);
    hipLaunchKernelGGL(k_expand, dim3(2048),  dim3(64),  0, stream, Yr, Yi, Aw);
    hipLaunchKernelGGL(k_fuse,   dim3(2048),  dim3(256), 0, stream,
                       x, Aw, skw, skb, m1w, m1b, m2w, m2b, out);
}

// Round 3
// 561.923 us; speedup vs baseline: 1.0973x; 1.0973x over previous
//
#include <hip/hip_runtime.h>
#include <math.h>

#define PI2_256 0.024543692606170259674f  // 2*pi/256

// ---------------------------------------------------------------------------
// Dims: B=8, C=64, H=256, W=256, M1=M2=16, MLP_HID=32
// Workspace (floats):
//   Xr [B][C][32][16]        off 0
//   Xi                       off 262144
//   Yr [B][16kx][32m][64o]   off 524288
//   Yi                       off 786432
//   Aw [B][H][32k][64o]      off 1048576  (4194304)
//   skwT[i][o] 64x64         off 5242880  (4096)
//   m1wT[o][j] 64x32         off 5246976  (2048)
//   m2wT[j][o] 32x64         off 5249024  (2048)
// total 5251072 floats ~= 21.0 MB
// ---------------------------------------------------------------------------

__device__ __forceinline__ void fma4(float4& a, float s, const float4& v) {
    a.x += s * v.x; a.y += s * v.y; a.z += s * v.z; a.w += s * v.w;
}

__device__ __forceinline__ float gelu_tanh(float v) {
    float t = 0.7978845608028654f * v * (1.0f + 0.044715f * v * v);
    float at = fabsf(t);
    float e = __expf(-2.0f * at);
    float th = (1.0f - e) / (1.0f + e);
    th = copysignf(th, t);
    return 0.5f * v * (1.0f + th);
}

// ---------------------------------------------------------------------------
// k_prep: one-time weight transposes into workspace (coalesced staging later).
// ---------------------------------------------------------------------------
__global__ __launch_bounds__(256) void k_prep(const float* __restrict__ skw,
                                              const float* __restrict__ m1w,
                                              const float* __restrict__ m2w,
                                              float* __restrict__ skwT,
                                              float* __restrict__ m1wT,
                                              float* __restrict__ m2wT) {
    int t = blockIdx.x * 256 + threadIdx.x;   // 8192 threads
    if (t < 4096) {
        int i = t >> 6, o = t & 63;           // skwT[i][o] = skw[o][i]
        skwT[t] = skw[o * 64 + i];
    } else if (t < 6144) {
        int s = t - 4096;
        int o = s >> 5, j = s & 31;           // m1wT[o][j] = m1w[j][o]
        m1wT[s] = m1w[j * 64 + o];
    } else {
        int s = t - 6144;
        int j = s >> 6, o = s & 63;           // m2wT[j][o] = m2w[o][j]
        m2wT[s] = m2w[o * 32 + j];
    }
}

// ---------------------------------------------------------------------------
// k_fwd: forward DFT (keep ky in {0..15}u{240..255}, kx in {0..15}).
// grid (64 c, 8 b), 256 threads. F-table in LDS + rotation recurrence over h.
// LDS ~51 KB -> 3 blocks/CU.
// ---------------------------------------------------------------------------
__global__ __launch_bounds__(256) void k_fwd(const float* __restrict__ x,
                                             float* __restrict__ Xr,
                                             float* __restrict__ Xi) {
    int b = blockIdx.y, c = blockIdx.x;
    const float* img = x + ((size_t)(b * 64 + c)) * 65536;
    __shared__ __align__(16) float xs[16 * 260];   // chunk rows (f4 stride 65)
    __shared__ __align__(16) float Ft[256 * 32];   // Ft[w][2kx]=cos, [2kx+1]=-sin
    __shared__ float xwr[256], xwi[256];           // [16 h][16 kx]

    int tid = threadIdx.x;
    int kx = tid & 15;
    int hl = tid >> 4;     // row in w-DFT phase
    int m16 = tid >> 4;    // mode in h-phase

    // ---- build Ft: thread (kxb, wg) fills 16 consecutive w for fixed kx ----
    {
        int kxb = tid & 15, wg = tid >> 4, w0 = wg * 16;
        float s0, c0;
        __sincosf(PI2_256 * (float)((kxb * w0) & 255), &s0, &c0);
        float cr = c0, ci = -s0;                       // e^{-i th(kx*w0)}
        float ps, pc;
        __sincosf(PI2_256 * (float)kxb, &ps, &pc);
        float pi_ = -ps;                               // step e^{-i th(kx)}
#pragma unroll
        for (int l = 0; l < 16; ++l) {
            int w = w0 + l;
            Ft[w * 32 + 2 * kxb]     = cr;
            Ft[w * 32 + 2 * kxb + 1] = ci;
            float nc = cr * pc - ci * pi_;
            ci = cr * pi_ + ci * pc;
            cr = nc;
        }
    }

    // h-phase rotation state (persists across chunks; h advances by 1)
    int f1 = m16, f2 = 240 + m16;
    float p1s, p1c, p2s, p2c;
    __sincosf(PI2_256 * (float)f1, &p1s, &p1c);
    __sincosf(PI2_256 * (float)(f2 & 255), &p2s, &p2c);
    float c1 = 1.f, s1 = 0.f, c2 = 1.f, s2 = 0.f;     // cos/sin(f*h*th)
    float a1r = 0.f, a1i = 0.f, a2r = 0.f, a2i = 0.f;

    for (int chunk = 0; chunk < 16; ++chunk) {
        int hbase = chunk * 16;
        for (int q = 0; q < 4; ++q) {
            int f4 = tid + q * 256;
            int row = f4 >> 6, col = f4 & 63;
            float4 v = ((const float4*)(img + (hbase + row) * 256))[col];
            ((float4*)xs)[row * 65 + col] = v;
        }
        __syncthreads();

        // ---- w-DFT: thread (hl, kx) reduces one row ----
        {
            const float4* xrow = (const float4*)(xs + hl * 260);
            const float2* F2 = (const float2*)Ft;
            float swr = 0.f, swi = 0.f;
#pragma unroll 4
            for (int w4 = 0; w4 < 64; ++w4) {
                float4 xv = xrow[w4];
                float2 f0 = F2[(w4 * 4 + 0) * 16 + kx];
                float2 f1_ = F2[(w4 * 4 + 1) * 16 + kx];
                float2 f2_ = F2[(w4 * 4 + 2) * 16 + kx];
                float2 f3 = F2[(w4 * 4 + 3) * 16 + kx];
                swr += xv.x * f0.x; swi += xv.x * f0.y;
                swr += xv.y * f1_.x; swi += xv.y * f1_.y;
                swr += xv.z * f2_.x; swi += xv.z * f2_.y;
                swr += xv.w * f3.x; swi += xv.w * f3.y;
            }
            xwr[hl * 16 + kx] = swr;
            xwi[hl * 16 + kx] = swi;
        }
        __syncthreads();

        // ---- h-accumulate with rotation recurrence ----
        for (int hh = 0; hh < 16; ++hh) {
            float wr = xwr[hh * 16 + kx], wi = xwi[hh * 16 + kx];
            a1r += wr * c1 + wi * s1;  a1i += wi * c1 - wr * s1;
            a2r += wr * c2 + wi * s2;  a2i += wi * c2 - wr * s2;
            float n1 = c1 * p1c - s1 * p1s; s1 = c1 * p1s + s1 * p1c; c1 = n1;
            float n2 = c2 * p2c - s2 * p2s; s2 = c2 * p2s + s2 * p2c; c2 = n2;
        }
        __syncthreads();
    }
    int base = ((b * 64 + c) * 32) * 16;
    Xr[base + m16 * 16 + kx]        = a1r;
    Xi[base + m16 * 16 + kx]        = a1i;
    Xr[base + (m16 + 16) * 16 + kx] = a2r;
    Xi[base + (m16 + 16) * 16 + kx] = a2i;
}

// ---------------------------------------------------------------------------
// k_mix: complex channel mix. grid (4 o-split, 32 m), 256 threads.
// Each weight element read exactly once from HBM; accumulate over all 8 b.
// ---------------------------------------------------------------------------
__global__ __launch_bounds__(256) void k_mix(const float* __restrict__ Xr,
                                             const float* __restrict__ Xi,
                                             const float* __restrict__ w1r,
                                             const float* __restrict__ w1i,
                                             const float* __restrict__ w2r,
                                             const float* __restrict__ w2i,
                                             float* __restrict__ Yr,
                                             float* __restrict__ Yi) {
    int ob = blockIdx.x;   // 0..3
    int m  = blockIdx.y;   // 0..31
    __shared__ float Xsr[8192], Xsi[8192];   // [b][i][kx] = (b*64+i)*16+kx
    int tid = threadIdx.x;
    for (int q = 0; q < 32; ++q) {
        int slot = tid + q * 256;
        int bb = slot >> 10, ii = (slot >> 4) & 63, kk = slot & 15;
        int idx = ((bb * 64 + ii) * 32 + m) * 16 + kk;
        Xsr[slot] = Xr[idx];
        Xsi[slot] = Xi[idx];
    }
    __syncthreads();

    const float* Wr; const float* Wi; int mm;
    if (m < 16) { Wr = w1r; Wi = w1i; mm = m; }
    else        { Wr = w2r; Wi = w2i; mm = m - 16; }

    int kx = tid & 15, og = tid >> 4;
    int o = ob * 16 + og;
    float ar[8] = {0,0,0,0,0,0,0,0}, ai[8] = {0,0,0,0,0,0,0,0};
    for (int i = 0; i < 64; ++i) {
        int widx = ((i * 64 + o) * 16 + mm) * 16 + kx;
        float wr = Wr[widx], wi = Wi[widx];
#pragma unroll
        for (int bb = 0; bb < 8; ++bb) {
            float xr  = Xsr[(bb << 10) + (i << 4) + kx];
            float xi2 = Xsi[(bb << 10) + (i << 4) + kx];
            ar[bb] += xr * wr - xi2 * wi;
            ai[bb] += xr * wi + xi2 * wr;
        }
    }
#pragma unroll
    for (int bb = 0; bb < 8; ++bb) {
        int yidx = ((bb * 16 + kx) * 32 + m) * 64 + o;
        Yr[yidx] = ar[bb];
        Yi[yidx] = ai[bb];
    }
}

// ---------------------------------------------------------------------------
// k_expand: expand modes along h (fold scale + Hermitian x2 + sign).
// grid 2048 = b(8)*kx(16)*hq(16), 256 threads: (o = tid&63, hg = tid>>6) x 4 h
// ---------------------------------------------------------------------------
__global__ __launch_bounds__(256) void k_expand(const float* __restrict__ Yr,
                                                const float* __restrict__ Yi,
                                                float* __restrict__ Aw) {
    int bid = blockIdx.x;
    int hq = bid & 15, kx = (bid >> 4) & 15, b = bid >> 8;
    int tid = threadIdx.x;
    int o = tid & 63, hg = tid >> 6;

    float yr[32], yi[32];
    int ybase = ((b * 16 + kx) * 32) * 64 + o;
#pragma unroll
    for (int mm = 0; mm < 32; ++mm) {
        yr[mm] = Yr[ybase + mm * 64];
        yi[mm] = Yi[ybase + mm * 64];
    }
    float sc = (kx == 0 ? 1.0f : 2.0f) * (1.0f / 65536.0f);

    for (int hl = 0; hl < 4; ++hl) {
        int h = hq * 16 + hg * 4 + hl;
        float sts, stc;
        __sincosf(PI2_256 * (float)h, &sts, &stc);  // step e^{+i 2pi h/256}
        float tc = 1.f, ts = 0.f, ur = 0.f, ui = 0.f;
#pragma unroll
        for (int mm = 0; mm < 16; ++mm) {
            ur += yr[mm] * tc - yi[mm] * ts;
            ui += yr[mm] * ts + yi[mm] * tc;
            float nc = tc * stc - ts * sts; ts = tc * sts + ts * stc; tc = nc;
        }
        { float s2, c2; __sincosf(PI2_256 * (float)((240 * h) & 255), &s2, &c2);
          tc = c2; ts = s2; }
#pragma unroll
        for (int mm = 16; mm < 32; ++mm) {
            ur += yr[mm] * tc - yi[mm] * ts;
            ui += yr[mm] * ts + yi[mm] * tc;
            float nc = tc * stc - ts * sts; ts = tc * sts + ts * stc; tc = nc;
        }
        int abase = ((b * 256 + h) * 32 + 2 * kx) * 64 + o;
        Aw[abase]      =  sc * ur;
        Aw[abase + 64] = -sc * ui;
    }
}

// ---------------------------------------------------------------------------
// k_fuse: spectral-recon + skip + bias + MLP(gelu) + residual.
// One block per (b,h). 256 threads = 4 waves; wave owns a 16-row o-block
// (phase 2: 8-row j-block); weights read as wave-uniform LDS broadcasts.
// LDS ~138 KB -> 1 block/CU.
// ---------------------------------------------------------------------------
__global__ __launch_bounds__(256, 1) void k_fuse(const float* __restrict__ x,
                                                 const float* __restrict__ Aw,
                                                 const float* __restrict__ skwT,
                                                 const float* __restrict__ skb,
                                                 const float* __restrict__ m1wT,
                                                 const float* __restrict__ m1b,
                                                 const float* __restrict__ m2wT,
                                                 const float* __restrict__ m2b,
                                                 float* __restrict__ out) {
    __shared__ __align__(16) float xs[64 * 260];  // x rows, then x1 (f4 str 65)
    __shared__ __align__(16) float Fb[32 * 260];  // cos/sin table, then h1
    __shared__ __align__(16) float Wp[96 * 64];   // [0..63]=skwT, [64..95]=A
    __shared__ __align__(16) float w1s[64 * 32];  // [o][j]
    __shared__ __align__(16) float w2s[32 * 64];  // [j][o]
    __shared__ float bs[64], b1s[32], b2s[64];

    int bid = blockIdx.x;
    int b = bid >> 8, h = bid & 255;
    int tid = threadIdx.x;
    int lane = tid & 63;
    int wid = tid >> 6;
    int ob = wid * 16;

    const float* xrow0 = x + ((size_t)(b * 64) * 256 + h) * 256;

    // ---- stage x rows (coalesced, conflict-free) ----
    for (int q = 0; q < 16; ++q) {
        int f4 = tid + q * 256;
        int row = f4 >> 6, col = f4 & 63;
        float4 v = ((const float4*)(xrow0 + (size_t)row * 65536))[col];
        ((float4*)xs)[row * 65 + col] = v;
    }
    // ---- stage Wp: skip rows then A rows (all contiguous) ----
    for (int q = 0; q < 16; ++q) {
        int slot = tid + q * 256;
        Wp[slot] = skwT[slot];
    }
    {
        const float* ab = Aw + ((size_t)(b * 256 + h) * 32) * 64;
        for (int q = 0; q < 8; ++q) {
            int slot = tid + q * 256;
            Wp[4096 + slot] = ab[slot];
        }
    }
    for (int q = 0; q < 8; ++q) { int s = tid + q * 256; w1s[s] = m1wT[s]; }
    for (int q = 0; q < 8; ++q) { int s = tid + q * 256; w2s[s] = m2wT[s]; }
    // ---- F table rows: Fb[2k][w]=cos, Fb[2k+1][w]=sin ----
    {
        int w = tid;   // 0..255
        float sw_, cw_;
        __sincosf(PI2_256 * (float)w, &sw_, &cw_);
        float cc = 1.f, ss = 0.f;
#pragma unroll
        for (int k = 0; k < 16; ++k) {
            Fb[(2 * k) * 260 + w]     = cc;
            Fb[(2 * k + 1) * 260 + w] = ss;
            float nc = cc * cw_ - ss * sw_;
            ss = cc * sw_ + ss * cw_;
            cc = nc;
        }
    }
    if (tid < 64) bs[tid]  = skb[tid];
    if (tid < 32) b1s[tid] = m1b[tid];
    if (tid < 64) b2s[tid] = m2b[tid];
    __syncthreads();

    // ============ phase 1: x1 = skip(x) + spectral + bias ============
    float4 acc[16];
#pragma unroll
    for (int i = 0; i < 16; ++i) acc[i] = make_float4(0, 0, 0, 0);

    for (int k = 0; k < 64; ++k) {
        const float* wrow = &Wp[k * 64 + ob];
        float4 wb0 = *(const float4*)(wrow);
        float4 wb1 = *(const float4*)(wrow + 4);
        float4 wb2 = *(const float4*)(wrow + 8);
        float4 wb3 = *(const float4*)(wrow + 12);
        float4 xv = ((const float4*)xs)[k * 65 + lane];
        fma4(acc[0],  wb0.x, xv); fma4(acc[1],  wb0.y, xv);
        fma4(acc[2],  wb0.z, xv); fma4(acc[3],  wb0.w, xv);
        fma4(acc[4],  wb1.x, xv); fma4(acc[5],  wb1.y, xv);
        fma4(acc[6],  wb1.z, xv); fma4(acc[7],  wb1.w, xv);
        fma4(acc[8],  wb2.x, xv); fma4(acc[9],  wb2.y, xv);
        fma4(acc[10], wb2.z, xv); fma4(acc[11], wb2.w, xv);
        fma4(acc[12], wb3.x, xv); fma4(acc[13], wb3.y, xv);
        fma4(acc[14], wb3.z, xv); fma4(acc[15], wb3.w, xv);
    }
    for (int k = 0; k < 32; ++k) {
        const float* wrow = &Wp[(64 + k) * 64 + ob];
        float4 wb0 = *(const float4*)(wrow);
        float4 wb1 = *(const float4*)(wrow + 4);
        float4 wb2 = *(const float4*)(wrow + 8);
        float4 wb3 = *(const float4*)(wrow + 12);
        float4 xv = ((const float4*)Fb)[k * 65 + lane];
        fma4(acc[0],  wb0.x, xv); fma4(acc[1],  wb0.y, xv);
        fma4(acc[2],  wb0.z, xv); fma4(acc[3],  wb0.w, xv);
        fma4(acc[4],  wb1.x, xv); fma4(acc[5],  wb1.y, xv);
        fma4(acc[6],  wb1.z, xv); fma4(acc[7],  wb1.w, xv);
        fma4(acc[8],  wb2.x, xv); fma4(acc[9],  wb2.y, xv);
        fma4(acc[10], wb2.z, xv); fma4(acc[11], wb2.w, xv);
        fma4(acc[12], wb3.x, xv); fma4(acc[13], wb3.y, xv);
        fma4(acc[14], wb3.z, xv); fma4(acc[15], wb3.w, xv);
    }
    __syncthreads();   // all reads of xs/Fb done
#pragma unroll
    for (int i = 0; i < 16; ++i) {
        int o = ob + i;
        float bb = bs[o];
        float4 v = acc[i];
        v.x += bb; v.y += bb; v.z += bb; v.w += bb;
        ((float4*)xs)[o * 65 + lane] = v;     // x1
    }
    __syncthreads();

    // ============ phase 2: h1 = gelu(w1 . x1 + b1) ============
    int jb = wid * 8;
    float4 a2[8];
#pragma unroll
    for (int i = 0; i < 8; ++i) a2[i] = make_float4(0, 0, 0, 0);

    for (int o = 0; o < 64; ++o) {
        const float* wrow = &w1s[o * 32 + jb];
        float4 wb0 = *(const float4*)(wrow);
        float4 wb1 = *(const float4*)(wrow + 4);
        float4 xv = ((const float4*)xs)[o * 65 + lane];
        fma4(a2[0], wb0.x, xv); fma4(a2[1], wb0.y, xv);
        fma4(a2[2], wb0.z, xv); fma4(a2[3], wb0.w, xv);
        fma4(a2[4], wb1.x, xv); fma4(a2[5], wb1.y, xv);
        fma4(a2[6], wb1.z, xv); fma4(a2[7], wb1.w, xv);
    }
#pragma unroll
    for (int i = 0; i < 8; ++i) {
        int j = jb + i;
        float bb = b1s[j];
        float4 v = a2[i];
        v.x = gelu_tanh(v.x + bb);
        v.y = gelu_tanh(v.y + bb);
        v.z = gelu_tanh(v.z + bb);
        v.w = gelu_tanh(v.w + bb);
        ((float4*)Fb)[j * 65 + lane] = v;     // h1
    }
    __syncthreads();

    // ============ phase 3: out = x + w2 . h1 + b2 ============
    float4 res[16];
#pragma unroll
    for (int i = 0; i < 16; ++i) {
        int o = ob + i;
        res[i] = ((const float4*)(x + (((size_t)(b * 64 + o)) * 256 + h) * 256))[lane];
    }
    float4 a3[16];
#pragma unroll
    for (int i = 0; i < 16; ++i) a3[i] = make_float4(0, 0, 0, 0);

    for (int j = 0; j < 32; ++j) {
        const float* wrow = &w2s[j * 64 + ob];
        float4 wb0 = *(const float4*)(wrow);
        float4 wb1 = *(const float4*)(wrow + 4);
        float4 wb2 = *(const float4*)(wrow + 8);
        float4 wb3 = *(const float4*)(wrow + 12);
        float4 xv = ((const float4*)Fb)[j * 65 + lane];
        fma4(a3[0],  wb0.x, xv); fma4(a3[1],  wb0.y, xv);
        fma4(a3[2],  wb0.z, xv); fma4(a3[3],  wb0.w, xv);
        fma4(a3[4],  wb1.x, xv); fma4(a3[5],  wb1.y, xv);
        fma4(a3[6],  wb1.z, xv); fma4(a3[7],  wb1.w, xv);
        fma4(a3[8],  wb2.x, xv); fma4(a3[9],  wb2.y, xv);
        fma4(a3[10], wb2.z, xv); fma4(a3[11], wb2.w, xv);
        fma4(a3[12], wb3.x, xv); fma4(a3[13], wb3.y, xv);
        fma4(a3[14], wb3.z, xv); fma4(a3[15], wb3.w, xv);
    }
#pragma unroll
    for (int i = 0; i < 16; ++i) {
        int o = ob + i;
        float bb = b2s[o];
        float4 v = a3[i];
        float4 r = res[i];
        v.x += bb + r.x; v.y += bb + r.y; v.z += bb + r.z; v.w += bb + r.w;
        ((float4*)(out + (((size_t)(b * 64 + o)) * 256 + h) * 256))[lane] = v;
    }
}

// ---------------------------------------------------------------------------
extern "C" void kernel_launch(void* const* d_in, const int* in_sizes, int n_in,
                              void* d_out, int out_size, void* d_ws, size_t ws_size,
                              hipStream_t stream) {
    const float* x   = (const float*)d_in[0];
    const float* w1r = (const float*)d_in[1];
    const float* w1i = (const float*)d_in[2];
    const float* w2r = (const float*)d_in[3];
    const float* w2i = (const float*)d_in[4];
    const float* skw = (const float*)d_in[5];
    const float* skb = (const float*)d_in[6];
    const float* m1w = (const float*)d_in[7];
    const float* m1b = (const float*)d_in[8];
    const float* m2w = (const float*)d_in[9];
    const float* m2b = (const float*)d_in[10];
    float* out = (float*)d_out;

    float* ws = (float*)d_ws;
    float* Xr   = ws;
    float* Xi   = ws + 262144;
    float* Yr   = ws + 524288;
    float* Yi   = ws + 786432;
    float* Aw   = ws + 1048576;
    float* skwT = ws + 5242880;
    float* m1wT = ws + 5246976;
    float* m2wT = ws + 5249024;

    hipLaunchKernelGGL(k_prep,   dim3(32),     dim3(256), 0, stream,
                       skw, m1w, m2w, skwT, m1wT, m2wT);
    hipLaunchKernelGGL(k_fwd,    dim3(64, 8),  dim3(256), 0, stream, x, Xr, Xi);
    hipLaunchKernelGGL(k_mix,    dim3(4, 32),  dim3(256), 0, stream,
                       Xr, Xi, w1r, w1i, w2r, w2i, Yr, Yi);
    hipLaunchKernelGGL(k_expand, dim3(2048),   dim3(256), 0, stream, Yr, Yi, Aw);
    hipLaunchKernelGGL(k_fuse,   dim3(2048),   dim3(256), 0, stream,
                       x, Aw, skwT, skb, m1wT, m1b, m2wT, m2b, out);
}